// Round 1
// baseline (3405.806 us; speedup 1.0000x reference)
//
#include <hip/hip_runtime.h>
#include <cstdint>
#include <cstddef>

typedef unsigned long long u64;
typedef unsigned int u32;

// ---------------- workspace layout (bytes) ----------------
// y0: 1024*40*40 f32, y1: 512*80*80 f32, y2: 256*160*160 f32
// boxes: 100800*85 f32, keys: 100800 u64, hist: 65536 u32,
// meta: 16 u32 (B, countAbove, cand_count,...), cand: 4096 u64, sel: 256 u32
#define OFF_Y0     ((size_t)0)
#define OFF_Y1     ((size_t)6553600)
#define OFF_Y2     ((size_t)19660800)
#define OFF_BOXES  ((size_t)45875200)
#define OFF_KEYS   ((size_t)80147200)
#define OFF_HIST   ((size_t)80953600)
#define OFF_META   ((size_t)81215744)
#define OFF_CAND   ((size_t)81215808)
#define OFF_SEL    ((size_t)81248576)
#define MEMSET_LEN ((size_t)(262144 + 64))   // hist + meta

#define NBOX 100800
#define CAND_CAP 4096

// ---------------- 3x3 conv, same padding ----------------
// block = 256 threads: 64 couts x 8x8 spatial tile. thread: 1 cout, 2x8 pixels.
// grid.x = (W/8)*(H/8), grid.y = C/64
__global__ __launch_bounds__(256) void conv3x3_kernel(
    const float* __restrict__ x, const float* __restrict__ w,
    const float* __restrict__ b, float* __restrict__ y,
    int C, int H, int W)
{
    const int tiles_x = W >> 3;
    const int ty0 = (blockIdx.x / tiles_x) * 8;
    const int tx0 = (blockIdx.x % tiles_x) * 8;
    const int co0 = blockIdx.y * 64;
    const int tid = threadIdx.x;
    const int col = tid & 63;           // cout within tile
    const int g   = tid >> 6;           // wave id -> row pair 2g,2g+1
    const int co  = co0 + col;
    const int HW  = H * W;

    __shared__ float xs[4][10][12];     // [cin][row][col], col pad to 12
    __shared__ float wsm[4][64][9];     // [cin][cout][tap]

    float acc[2][8];
    {
        float bv = b[co];
        #pragma unroll
        for (int r = 0; r < 2; r++)
            #pragma unroll
            for (int c = 0; c < 8; c++) acc[r][c] = bv;
    }

    for (int ci0 = 0; ci0 < C; ci0 += 4) {
        __syncthreads();
        // stage input patch 4 x 10 x 10 (zero-padded at borders)
        for (int idx = tid; idx < 4 * 100; idx += 256) {
            int ci = idx / 100; int rem = idx - ci * 100;
            int r = rem / 10, c = rem - r * 10;
            int gy = ty0 - 1 + r, gx = tx0 - 1 + c;
            float v = 0.0f;
            if (gy >= 0 && gy < H && gx >= 0 && gx < W)
                v = x[(size_t)(ci0 + ci) * HW + gy * W + gx];
            xs[ci][r][c] = v;
        }
        // stage weights 4 x 64 x 9
        for (int idx = tid; idx < 4 * 64 * 9; idx += 256) {
            int ci = idx / 576; int rem = idx - ci * 576;
            int cc = rem / 9, tap = rem - cc * 9;
            wsm[ci][cc][tap] = w[((size_t)(co0 + cc) * C + ci0 + ci) * 9 + tap];
        }
        __syncthreads();
        #pragma unroll
        for (int ci = 0; ci < 4; ci++) {
            float wr[9];
            #pragma unroll
            for (int t = 0; t < 9; t++) wr[t] = wsm[ci][col][t];
            float xr[4][10];
            #pragma unroll
            for (int r = 0; r < 4; r++)
                #pragma unroll
                for (int c = 0; c < 10; c++) xr[r][c] = xs[ci][2 * g + r][c];
            #pragma unroll
            for (int r = 0; r < 2; r++)
                #pragma unroll
                for (int c = 0; c < 8; c++) {
                    float s = acc[r][c];
                    #pragma unroll
                    for (int dy = 0; dy < 3; dy++)
                        #pragma unroll
                        for (int dx = 0; dx < 3; dx++)
                            s = fmaf(xr[r + dy][c + dx], wr[dy * 3 + dx], s);
                    acc[r][c] = s;
                }
        }
    }
    #pragma unroll
    for (int r = 0; r < 2; r++) {
        int gy = ty0 + 2 * g + r;
        #pragma unroll
        for (int c = 0; c < 8; c++)
            y[(size_t)co * HW + gy * W + tx0 + c] = acc[r][c];
    }
}

// ---------------- 1x1 conv + sigmoid + decode, fused ----------------
// block = 256 threads: 64 couts x 64 pixels. thread: 4 couts x 4 pixels.
// grid.x = HW/64, grid.y = 4 (couts 0..255, 255 is padding)
__global__ __launch_bounds__(256) void conv1x1_decode_kernel(
    const float* __restrict__ y, const float* __restrict__ w,
    const float* __restrict__ b, float* __restrict__ boxes,
    u64* __restrict__ keys,
    int C, int H, int W, int box_base, float ratio,
    float a0w, float a0h, float a1w, float a1h, float a2w, float a2h)
{
    const int HW = H * W;
    const int p0 = blockIdx.x * 64;
    const int co0 = blockIdx.y * 64;
    const int tid = threadIdx.x;
    const int p4 = (tid & 15) * 4;
    const int c4 = (tid >> 4) * 4;

    __shared__ float ys[16][64];
    __shared__ float wts[16][68];   // pad 68 to keep 16B alignment + fewer conflicts

    float acc[4][4];
    #pragma unroll
    for (int i = 0; i < 4; i++) {
        int co = co0 + c4 + i;
        float bv = (co < 255) ? b[co] : 0.0f;
        #pragma unroll
        for (int j = 0; j < 4; j++) acc[i][j] = bv;
    }

    for (int ci0 = 0; ci0 < C; ci0 += 16) {
        __syncthreads();
        for (int idx = tid; idx < 16 * 64; idx += 256) {
            int ci = idx >> 6, p = idx & 63;
            ys[ci][p] = y[(size_t)(ci0 + ci) * HW + p0 + p];
        }
        for (int idx = tid; idx < 16 * 64; idx += 256) {
            int co = idx >> 4, ci = idx & 15;
            float v = 0.0f;
            if (co0 + co < 255) v = w[(size_t)(co0 + co) * C + ci0 + ci];
            wts[ci][co] = v;
        }
        __syncthreads();
        #pragma unroll
        for (int ci = 0; ci < 16; ci++) {
            float4 xv = *reinterpret_cast<const float4*>(&ys[ci][p4]);
            float4 wv = *reinterpret_cast<const float4*>(&wts[ci][c4]);
            const float xa[4] = {xv.x, xv.y, xv.z, xv.w};
            const float wa[4] = {wv.x, wv.y, wv.z, wv.w};
            #pragma unroll
            for (int i = 0; i < 4; i++)
                #pragma unroll
                for (int j = 0; j < 4; j++)
                    acc[i][j] = fmaf(wa[i], xa[j], acc[i][j]);
        }
    }

    const float aw[3] = {a0w, a1w, a2w};
    const float ah[3] = {a0h, a1h, a2h};
    #pragma unroll
    for (int i = 0; i < 4; i++) {
        int co = co0 + c4 + i;
        if (co >= 255) continue;
        int a = co / 85;
        int c = co - a * 85;
        #pragma unroll
        for (int j = 0; j < 4; j++) {
            float v = acc[i][j];
            float s = 1.0f / (1.0f + expf(-v));
            int p = p0 + p4 + j;
            int py = p / W, px = p - (p / W) * W;
            float o;
            if (c == 0)      o = (s * 2.0f - 0.5f + (float)px) * ratio;
            else if (c == 1) o = (s * 2.0f - 0.5f + (float)py) * ratio;
            else if (c == 2) { float t = s * 2.0f; o = t * t * aw[a]; }
            else if (c == 3) { float t = s * 2.0f; o = t * t * ah[a]; }
            else             o = s;
            size_t bi = (size_t)box_base + ((size_t)a * H + py) * W + px;
            boxes[bi * 85 + c] = o;
            if (c == 4)
                keys[bi] = ((u64)__float_as_uint(s) << 32) |
                           (u64)(0xFFFFFFFFu - (u32)bi);
        }
    }
}

// ---------------- top-256 selection ----------------
__global__ __launch_bounds__(256) void hist_kernel(const u64* __restrict__ keys,
                                                   u32* __restrict__ hist, int n)
{
    int i = blockIdx.x * blockDim.x + threadIdx.x;
    if (i < n) {
        u32 bucket = (u32)(keys[i] >> 48);   // top 16 bits of score bits
        atomicAdd(&hist[bucket], 1u);
    }
}

__global__ __launch_bounds__(256) void select_kernel(const u32* __restrict__ hist,
                                                     u32* __restrict__ meta)
{
    __shared__ u32 csum[256];
    int t = threadIdx.x;
    u32 s = 0;
    for (int i = 0; i < 256; i++) s += hist[t * 256 + i];
    csum[t] = s;
    __syncthreads();
    if (t == 0) {
        u32 cum = 0; int chunk = 255;
        for (; chunk > 0; chunk--) {
            if (cum + csum[chunk] >= 256u) break;
            cum += csum[chunk];
        }
        int B = chunk * 256;
        u32 cumAbove = cum;
        for (int bb = chunk * 256 + 255; bb >= chunk * 256; bb--) {
            u32 h = hist[bb];
            if (cumAbove + h >= 256u) { B = bb; break; }
            cumAbove += h;
        }
        meta[0] = (u32)B;
        meta[1] = cumAbove;
    }
}

__global__ __launch_bounds__(256) void compact_kernel(
    const u64* __restrict__ keys, int n, const u32* __restrict__ meta,
    u64* __restrict__ cand, u32* __restrict__ count)
{
    int i = blockIdx.x * blockDim.x + threadIdx.x;
    if (i < n) {
        u64 k = keys[i];
        if ((u32)(k >> 48) >= meta[0]) {
            u32 pos = atomicAdd(count, 1u);
            if (pos < CAND_CAP) cand[pos] = k;
        }
    }
}

__global__ __launch_bounds__(1024) void sort_select_kernel(
    const u64* __restrict__ cand, const u32* __restrict__ meta,
    u32* __restrict__ sel)
{
    __shared__ u64 sk[CAND_CAP];
    int n = (int)meta[2];
    if (n > CAND_CAP) n = CAND_CAP;
    for (int i = threadIdx.x; i < CAND_CAP; i += 1024)
        sk[i] = (i < n) ? cand[i] : 0ull;
    __syncthreads();
    for (int k = 2; k <= CAND_CAP; k <<= 1) {
        for (int j = k >> 1; j > 0; j >>= 1) {
            for (int i = threadIdx.x; i < CAND_CAP; i += 1024) {
                int ixj = i ^ j;
                if (ixj > i) {
                    u64 a = sk[i], c = sk[ixj];
                    bool sw = ((i & k) == 0) ? (a > c) : (a < c);  // ascending
                    if (sw) { sk[i] = c; sk[ixj] = a; }
                }
            }
            __syncthreads();
        }
    }
    if (threadIdx.x < 256) {
        u64 k = sk[CAND_CAP - 1 - threadIdx.x];
        sel[threadIdx.x] = 0xFFFFFFFFu - (u32)(k & 0xFFFFFFFFull);
    }
}

__global__ __launch_bounds__(128) void gather_kernel(
    const float* __restrict__ boxes, const u32* __restrict__ sel,
    float* __restrict__ out)
{
    int bsel = blockIdx.x, c = threadIdx.x;
    if (c < 85) out[(size_t)bsel * 85 + c] = boxes[(size_t)sel[bsel] * 85 + c];
}

// ---------------- launch ----------------
extern "C" void kernel_launch(void* const* d_in, const int* in_sizes, int n_in,
                              void* d_out, int out_size, void* d_ws, size_t ws_size,
                              hipStream_t stream)
{
    const float* feat0 = (const float*)d_in[0];   // (256,160,160)
    const float* feat1 = (const float*)d_in[1];   // (512,80,80)
    const float* feat2 = (const float*)d_in[2];   // (1024,40,40)
    const float* w3_0 = (const float*)d_in[3];  const float* b3_0 = (const float*)d_in[4];
    const float* w1_0 = (const float*)d_in[5];  const float* b1_0 = (const float*)d_in[6];
    const float* w3_1 = (const float*)d_in[7];  const float* b3_1 = (const float*)d_in[8];
    const float* w1_1 = (const float*)d_in[9];  const float* b1_1 = (const float*)d_in[10];
    const float* w3_2 = (const float*)d_in[11]; const float* b3_2 = (const float*)d_in[12];
    const float* w1_2 = (const float*)d_in[13]; const float* b1_2 = (const float*)d_in[14];

    char* ws = (char*)d_ws;
    float* y0    = (float*)(ws + OFF_Y0);
    float* y1    = (float*)(ws + OFF_Y1);
    float* y2    = (float*)(ws + OFF_Y2);
    float* boxes = (float*)(ws + OFF_BOXES);
    u64*   keys  = (u64*)  (ws + OFF_KEYS);
    u32*   hist  = (u32*)  (ws + OFF_HIST);
    u32*   meta  = (u32*)  (ws + OFF_META);
    u64*   cand  = (u64*)  (ws + OFF_CAND);
    u32*   sel   = (u32*)  (ws + OFF_SEL);

    hipMemsetAsync(ws + OFF_HIST, 0, MEMSET_LEN, stream);

    dim3 blk(256);
    // head 0: feat2 (1024ch, 40x40)
    conv3x3_kernel<<<dim3(25, 16), blk, 0, stream>>>(feat2, w3_0, b3_0, y0, 1024, 40, 40);
    // head 1: feat1 (512ch, 80x80)
    conv3x3_kernel<<<dim3(100, 8), blk, 0, stream>>>(feat1, w3_1, b3_1, y1, 512, 80, 80);
    // head 2: feat0 (256ch, 160x160)
    conv3x3_kernel<<<dim3(400, 4), blk, 0, stream>>>(feat0, w3_2, b3_2, y2, 256, 160, 160);

    conv1x1_decode_kernel<<<dim3(25, 4), blk, 0, stream>>>(
        y0, w1_0, b1_0, boxes, keys, 1024, 40, 40, 0, 32.0f,
        116.0f, 90.0f, 156.0f, 198.0f, 373.0f, 326.0f);
    conv1x1_decode_kernel<<<dim3(100, 4), blk, 0, stream>>>(
        y1, w1_1, b1_1, boxes, keys, 512, 80, 80, 4800, 16.0f,
        30.0f, 61.0f, 62.0f, 45.0f, 59.0f, 119.0f);
    conv1x1_decode_kernel<<<dim3(400, 4), blk, 0, stream>>>(
        y2, w1_2, b1_2, boxes, keys, 256, 160, 160, 24000, 8.0f,
        10.0f, 13.0f, 16.0f, 30.0f, 33.0f, 23.0f);

    hist_kernel<<<(NBOX + 255) / 256, blk, 0, stream>>>(keys, hist, NBOX);
    select_kernel<<<1, blk, 0, stream>>>(hist, meta);
    compact_kernel<<<(NBOX + 255) / 256, blk, 0, stream>>>(keys, NBOX, meta, cand, meta + 2);
    sort_select_kernel<<<1, dim3(1024), 0, stream>>>(cand, meta, sel);
    gather_kernel<<<256, dim3(128), 0, stream>>>(boxes, sel, (float*)d_out);
}

// Round 2
// 1014.805 us; speedup vs baseline: 3.3561x; 3.3561x over previous
//
#include <hip/hip_runtime.h>
#include <cstdint>
#include <cstddef>

typedef unsigned long long u64;
typedef unsigned int u32;
typedef __attribute__((ext_vector_type(8))) short short8;
typedef __attribute__((ext_vector_type(4))) float f32x4;

#define NBOX 100800
#define CAND_CAP 4096

// ---------------- workspace layout (bytes) ----------------
#define OFF_WTH0 ((size_t)0)          // 1024*9*1024*2 = 18874368
#define OFF_WTH1 ((size_t)18874368)   // 512*9*512*2  = 4718592
#define OFF_WTH2 ((size_t)23592960)   // 256*9*256*2  = 1179648
#define OFF_WTL0 ((size_t)24772608)
#define OFF_WTL1 ((size_t)43646976)
#define OFF_WTL2 ((size_t)48365568)
#define OFF_Y0   ((size_t)49545216)   // 1024*1600*4  = 6553600
#define OFF_Y1   ((size_t)56098816)   // 512*6400*4   = 13107200
#define OFF_Y2   ((size_t)69206016)   // 256*25600*4  = 26214400
#define OFF_KEYS ((size_t)95420416)   // 100800*8
#define OFF_HIST ((size_t)96226816)   // 65536*4
#define OFF_META ((size_t)96488960)   // 64
#define OFF_CAND ((size_t)96489024)   // 4096*8
#define OFF_SEL  ((size_t)96521792)   // 1024

// ---------------- bf16 helpers (RNE, finite inputs) ----------------
__device__ __forceinline__ short f2bf(float f) {
    u32 u = __float_as_uint(f);
    u = (u + 0x7fffu + ((u >> 16) & 1u)) >> 16;
    return (short)u;
}
__device__ __forceinline__ float bf2f(short h) {
    return __uint_as_float(((u32)(unsigned short)h) << 16);
}

// ---------------- weight prep: (co,ci,3,3) f32 -> [co][tap][ci] bf16 hi/lo ----
__global__ __launch_bounds__(256) void prep_w_kernel(
    const float* __restrict__ w, short* __restrict__ wh, short* __restrict__ wl, int C)
{
    __shared__ float ws_[2304];
    int chunks = C >> 8;
    int co = blockIdx.x / chunks;
    int ci0 = (blockIdx.x % chunks) << 8;
    size_t base = ((size_t)co * C + ci0) * 9;
    for (int idx = threadIdx.x; idx < 2304; idx += 256) ws_[idx] = w[base + idx];
    __syncthreads();
    for (int idx = threadIdx.x; idx < 2304; idx += 256) {
        int tap = idx >> 8, ci = idx & 255;
        float v = ws_[ci * 9 + tap];
        short h = f2bf(v);
        short l = f2bf(v - bf2f(h));
        size_t o = ((size_t)co * 9 + tap) * C + ci0 + ci;
        wh[o] = h; wl[o] = l;
    }
}

// ---------------- bias init (for split-K atomic heads) ----------------
__global__ __launch_bounds__(256) void binit_kernel(float* y, const float* b, int HW, int n)
{
    int i = blockIdx.x * 256 + threadIdx.x;
    if (i < n) y[i] = b[i / HW];
}

// ---------------- 3x3 conv as implicit GEMM, bf16 MFMA, hi/lo 3-pass --------
// block: 256 thr = 4 waves; tile 128 couts x 128 pixels (8 rows x 16 cols).
// grid: (tiles_y*tiles_x, M/128, Z)  Z = tap split; Z>1 -> atomicAdd into
// bias-preinit y, Z==1 -> store acc+bias.
__global__ __launch_bounds__(256) void conv3x3_mfma(
    const float* __restrict__ x, const short* __restrict__ wth,
    const short* __restrict__ wtl, const float* __restrict__ bias,
    float* __restrict__ y, int C, int H, int W)
{
    const int HW = H * W;
    const int tiles_x = (W + 15) >> 4;
    const int py0 = (blockIdx.x / tiles_x) * 8;
    const int px0 = (blockIdx.x % tiles_x) * 16;
    const int co0 = blockIdx.y * 128;
    const int Z = gridDim.z;
    const int tap_lo = (blockIdx.z * 9) / Z;
    const int tap_hi = ((blockIdx.z + 1) * 9) / Z;
    const bool atomic_mode = (Z > 1);

    const int tid = threadIdx.x;
    const int lane = tid & 63;
    const int wave = tid >> 6;
    const int quad = lane >> 4;
    const int l15 = lane & 15;
    const int wm = wave >> 1, wn = wave & 1;

    // rows padded to 40 shorts (80 B) -> conflict-free b128 reads/writes
    __shared__ short As_hi[128 * 40];
    __shared__ short As_lo[128 * 40];
    __shared__ short Bs_hi[128 * 40];
    __shared__ short Bs_lo[128 * 40];

    f32x4 acc[4][4];
    #pragma unroll
    for (int i = 0; i < 4; i++)
        #pragma unroll
        for (int j = 0; j < 4; j++) acc[i][j] = (f32x4){0.f, 0.f, 0.f, 0.f};

    // B staging mapping: thread -> (n, k half)
    const int bn = tid & 127;
    const int bk2 = tid >> 7;          // k = bk2*16 .. +16
    const int bly = bn >> 4, blx = bn & 15;

    for (int tap = tap_lo; tap < tap_hi; ++tap) {
        const int dy = tap / 3 - 1, dx = tap % 3 - 1;
        const int spy = py0 + bly + dy, spx = px0 + blx + dx;
        const bool inb = (spy >= 0) && (spy < H) && (spx >= 0) && (spx < W);
        const float* xsrc = inb ? (x + (size_t)bk2 * 16 * HW + (size_t)spy * W + spx)
                                : (const float*)0;

        for (int ci0 = 0; ci0 < C; ci0 += 32) {
            __syncthreads();
            // ---- stage A (weights, bf16 hi/lo, [m][k] rows of 32) ----
            #pragma unroll
            for (int i = 0; i < 2; i++) {
                int slot = i * 256 + tid;
                int m = slot >> 2, ch = slot & 3;
                size_t go = ((size_t)(co0 + m) * 9 + tap) * C + ci0 + ch * 8;
                *(short8*)&As_hi[m * 40 + ch * 8] = *(const short8*)(wth + go);
                *(short8*)&As_lo[m * 40 + ch * 8] = *(const short8*)(wtl + go);
            }
            // ---- stage B (shifted input, fp32 -> bf16 hi/lo on the fly) ----
            {
                short8 h0 = {0,0,0,0,0,0,0,0}, h1 = {0,0,0,0,0,0,0,0};
                short8 l0 = {0,0,0,0,0,0,0,0}, l1 = {0,0,0,0,0,0,0,0};
                if (inb) {
                    const float* xp = xsrc + (size_t)ci0 * HW;
                    #pragma unroll
                    for (int k = 0; k < 8; k++) {
                        float v = xp[(size_t)k * HW];
                        short h = f2bf(v); short l = f2bf(v - bf2f(h));
                        h0[k] = h; l0[k] = l;
                    }
                    #pragma unroll
                    for (int k = 0; k < 8; k++) {
                        float v = xp[(size_t)(k + 8) * HW];
                        short h = f2bf(v); short l = f2bf(v - bf2f(h));
                        h1[k] = h; l1[k] = l;
                    }
                }
                int bo = bn * 40 + bk2 * 16;
                *(short8*)&Bs_hi[bo]     = h0;
                *(short8*)&Bs_hi[bo + 8] = h1;
                *(short8*)&Bs_lo[bo]     = l0;
                *(short8*)&Bs_lo[bo + 8] = l1;
            }
            __syncthreads();
            // ---- fragments + MFMA ----
            short8 ah[4], al[4], bh[4], bl[4];
            #pragma unroll
            for (int mt = 0; mt < 4; mt++) {
                int ro = (wm * 64 + mt * 16 + l15) * 40 + quad * 8;
                ah[mt] = *(const short8*)&As_hi[ro];
                al[mt] = *(const short8*)&As_lo[ro];
            }
            #pragma unroll
            for (int nt = 0; nt < 4; nt++) {
                int ro = (wn * 64 + nt * 16 + l15) * 40 + quad * 8;
                bh[nt] = *(const short8*)&Bs_hi[ro];
                bl[nt] = *(const short8*)&Bs_lo[ro];
            }
            #pragma unroll
            for (int mt = 0; mt < 4; mt++)
                #pragma unroll
                for (int nt = 0; nt < 4; nt++) {
                    acc[mt][nt] = __builtin_amdgcn_mfma_f32_16x16x32_bf16(ah[mt], bh[nt], acc[mt][nt], 0, 0, 0);
                    acc[mt][nt] = __builtin_amdgcn_mfma_f32_16x16x32_bf16(ah[mt], bl[nt], acc[mt][nt], 0, 0, 0);
                    acc[mt][nt] = __builtin_amdgcn_mfma_f32_16x16x32_bf16(al[mt], bh[nt], acc[mt][nt], 0, 0, 0);
                }
        }
    }

    // ---- epilogue: D[row=quad*4+r][col=l15] ----
    #pragma unroll
    for (int nt = 0; nt < 4; nt++) {
        int n = wn * 64 + nt * 16 + l15;
        int py = py0 + (n >> 4), px = px0 + (n & 15);
        if (px < W) {
            #pragma unroll
            for (int mt = 0; mt < 4; mt++) {
                #pragma unroll
                for (int r = 0; r < 4; r++) {
                    int co = co0 + wm * 64 + mt * 16 + quad * 4 + r;
                    size_t o = (size_t)co * HW + (size_t)py * W + px;
                    float v = acc[mt][nt][r];
                    if (atomic_mode) atomicAdd(&y[o], v);
                    else             y[o] = v + bias[co];
                }
            }
        }
    }
}

// ---------------- objectness-only 1x1 conv + key write ----------------
__global__ __launch_bounds__(256) void obj_kernel(
    const float* __restrict__ y, const float* __restrict__ w1,
    const float* __restrict__ b1, u64* __restrict__ keys,
    int C, int HW, int base)
{
    __shared__ float wv[3 * 1024];
    for (int idx = threadIdx.x; idx < 3 * C; idx += 256)
        wv[idx] = w1[((size_t)(idx / C) * 85 + 4) * C + (idx % C)];
    __syncthreads();
    int p = blockIdx.x * 256 + threadIdx.x;
    if (p >= HW) return;
    float a0 = b1[4], a1 = b1[89], a2 = b1[174];
    const float* yp = y + p;
    for (int ci = 0; ci < C; ci++) {
        float v = yp[(size_t)ci * HW];
        a0 = fmaf(v, wv[ci], a0);
        a1 = fmaf(v, wv[C + ci], a1);
        a2 = fmaf(v, wv[2 * C + ci], a2);
    }
    float sc[3] = {a0, a1, a2};
    #pragma unroll
    for (int a = 0; a < 3; a++) {
        float s = 1.0f / (1.0f + expf(-sc[a]));
        u32 bi = (u32)(base + a * HW + p);
        keys[bi] = ((u64)__float_as_uint(s) << 32) | (u64)(0xFFFFFFFFu - bi);
    }
}

// ---------------- top-256 selection (unchanged from R0, passed) -------------
__global__ __launch_bounds__(256) void hist_kernel(const u64* __restrict__ keys,
                                                   u32* __restrict__ hist, int n)
{
    int i = blockIdx.x * blockDim.x + threadIdx.x;
    if (i < n) atomicAdd(&hist[(u32)(keys[i] >> 48)], 1u);
}

__global__ __launch_bounds__(256) void select_kernel(const u32* __restrict__ hist,
                                                     u32* __restrict__ meta)
{
    __shared__ u32 csum[256];
    int t = threadIdx.x;
    u32 s = 0;
    for (int i = 0; i < 256; i++) s += hist[t * 256 + i];
    csum[t] = s;
    __syncthreads();
    if (t == 0) {
        u32 cum = 0; int chunk = 255;
        for (; chunk > 0; chunk--) {
            if (cum + csum[chunk] >= 256u) break;
            cum += csum[chunk];
        }
        int B = chunk * 256;
        u32 cumAbove = cum;
        for (int bb = chunk * 256 + 255; bb >= chunk * 256; bb--) {
            u32 h = hist[bb];
            if (cumAbove + h >= 256u) { B = bb; break; }
            cumAbove += h;
        }
        meta[0] = (u32)B;
        meta[1] = cumAbove;
    }
}

__global__ __launch_bounds__(256) void compact_kernel(
    const u64* __restrict__ keys, int n, const u32* __restrict__ meta,
    u64* __restrict__ cand, u32* __restrict__ count)
{
    int i = blockIdx.x * blockDim.x + threadIdx.x;
    if (i < n) {
        u64 k = keys[i];
        if ((u32)(k >> 48) >= meta[0]) {
            u32 pos = atomicAdd(count, 1u);
            if (pos < CAND_CAP) cand[pos] = k;
        }
    }
}

__global__ __launch_bounds__(1024) void sort_select_kernel(
    const u64* __restrict__ cand, const u32* __restrict__ meta,
    u32* __restrict__ sel)
{
    __shared__ u64 sk[CAND_CAP];
    int n = (int)meta[2];
    if (n > CAND_CAP) n = CAND_CAP;
    for (int i = threadIdx.x; i < CAND_CAP; i += 1024)
        sk[i] = (i < n) ? cand[i] : 0ull;
    __syncthreads();
    for (int k = 2; k <= CAND_CAP; k <<= 1) {
        for (int j = k >> 1; j > 0; j >>= 1) {
            for (int i = threadIdx.x; i < CAND_CAP; i += 1024) {
                int ixj = i ^ j;
                if (ixj > i) {
                    u64 a = sk[i], c = sk[ixj];
                    bool sw = ((i & k) == 0) ? (a > c) : (a < c);
                    if (sw) { sk[i] = c; sk[ixj] = a; }
                }
            }
            __syncthreads();
        }
    }
    if (threadIdx.x < 256) {
        u64 k = sk[CAND_CAP - 1 - threadIdx.x];
        sel[threadIdx.x] = 0xFFFFFFFFu - (u32)(k & 0xFFFFFFFFull);
    }
}

// ---------------- final: full 85-ch 1x1 conv + decode for the 256 winners ---
__global__ __launch_bounds__(256) void final_kernel(
    const float* __restrict__ y0, const float* __restrict__ y1, const float* __restrict__ y2,
    const float* __restrict__ w10, const float* __restrict__ w11, const float* __restrict__ w12,
    const float* __restrict__ b10, const float* __restrict__ b11, const float* __restrict__ b12,
    const u32* __restrict__ sel, float* __restrict__ out)
{
    int b = blockIdx.x;
    u32 bi = sel[b];
    const float *y, *w1, *b1;
    int C, H, W, base; float ratio;
    float anchs[6];
    if (bi < 4800u) {
        y = y0; w1 = w10; b1 = b10; C = 1024; H = 40; W = 40; base = 0; ratio = 32.f;
        anchs[0]=116.f; anchs[1]=90.f; anchs[2]=156.f; anchs[3]=198.f; anchs[4]=373.f; anchs[5]=326.f;
    } else if (bi < 24000u) {
        y = y1; w1 = w11; b1 = b11; C = 512; H = 80; W = 80; base = 4800; ratio = 16.f;
        anchs[0]=30.f; anchs[1]=61.f; anchs[2]=62.f; anchs[3]=45.f; anchs[4]=59.f; anchs[5]=119.f;
    } else {
        y = y2; w1 = w12; b1 = b12; C = 256; H = 160; W = 160; base = 24000; ratio = 8.f;
        anchs[0]=10.f; anchs[1]=13.f; anchs[2]=16.f; anchs[3]=30.f; anchs[4]=33.f; anchs[5]=23.f;
    }
    int HW = H * W;
    int r = (int)bi - base;
    int a = r / HW, p = r % HW;
    __shared__ float ys[256];
    int c = threadIdx.x;
    float acc = 0.f;
    const float* wrow = w1 + (size_t)(a * 85 + (c < 85 ? c : 0)) * C;
    for (int ci0 = 0; ci0 < C; ci0 += 256) {
        __syncthreads();
        ys[c] = y[(size_t)(ci0 + c) * HW + p];
        __syncthreads();
        if (c < 85)
            for (int ci = 0; ci < 256; ci++) acc = fmaf(ys[ci], wrow[ci0 + ci], acc);
    }
    if (c < 85) {
        float v = acc + b1[a * 85 + c];
        float s = 1.0f / (1.0f + expf(-v));
        int py = p / W, px = p - (p / W) * W;
        float o;
        if (c == 0)      o = (s * 2.0f - 0.5f + (float)px) * ratio;
        else if (c == 1) o = (s * 2.0f - 0.5f + (float)py) * ratio;
        else if (c == 2) { float t = s * 2.0f; o = t * t * anchs[a * 2]; }
        else if (c == 3) { float t = s * 2.0f; o = t * t * anchs[a * 2 + 1]; }
        else             o = s;
        out[(size_t)b * 85 + c] = o;
    }
}

// ---------------- launch ----------------
extern "C" void kernel_launch(void* const* d_in, const int* in_sizes, int n_in,
                              void* d_out, int out_size, void* d_ws, size_t ws_size,
                              hipStream_t stream)
{
    const float* feat0 = (const float*)d_in[0];   // (256,160,160)
    const float* feat1 = (const float*)d_in[1];   // (512,80,80)
    const float* feat2 = (const float*)d_in[2];   // (1024,40,40)
    const float* w3_0 = (const float*)d_in[3];  const float* b3_0 = (const float*)d_in[4];
    const float* w1_0 = (const float*)d_in[5];  const float* b1_0 = (const float*)d_in[6];
    const float* w3_1 = (const float*)d_in[7];  const float* b3_1 = (const float*)d_in[8];
    const float* w1_1 = (const float*)d_in[9];  const float* b1_1 = (const float*)d_in[10];
    const float* w3_2 = (const float*)d_in[11]; const float* b3_2 = (const float*)d_in[12];
    const float* w1_2 = (const float*)d_in[13]; const float* b1_2 = (const float*)d_in[14];

    char* ws = (char*)d_ws;
    short* wth0 = (short*)(ws + OFF_WTH0);
    short* wth1 = (short*)(ws + OFF_WTH1);
    short* wth2 = (short*)(ws + OFF_WTH2);
    short* wtl0 = (short*)(ws + OFF_WTL0);
    short* wtl1 = (short*)(ws + OFF_WTL1);
    short* wtl2 = (short*)(ws + OFF_WTL2);
    float* y0   = (float*)(ws + OFF_Y0);
    float* y1   = (float*)(ws + OFF_Y1);
    float* y2   = (float*)(ws + OFF_Y2);
    u64*   keys = (u64*)  (ws + OFF_KEYS);
    u32*   hist = (u32*)  (ws + OFF_HIST);
    u32*   meta = (u32*)  (ws + OFF_META);
    u64*   cand = (u64*)  (ws + OFF_CAND);
    u32*   sel  = (u32*)  (ws + OFF_SEL);

    hipMemsetAsync(ws + OFF_HIST, 0, 262144 + 64, stream);

    // weight transforms (f32 -> tap-major bf16 hi/lo)
    prep_w_kernel<<<4096, 256, 0, stream>>>(w3_0, wth0, wtl0, 1024);
    prep_w_kernel<<<1024, 256, 0, stream>>>(w3_1, wth1, wtl1, 512);
    prep_w_kernel<<<256,  256, 0, stream>>>(w3_2, wth2, wtl2, 256);

    // bias pre-init for split-K atomic heads
    binit_kernel<<<6400,  256, 0, stream>>>(y0, b3_0, 1600, 1024 * 1600);
    binit_kernel<<<12800, 256, 0, stream>>>(y1, b3_1, 6400, 512 * 6400);

    // 3x3 convs (MFMA)
    conv3x3_mfma<<<dim3(15, 8, 3),  256, 0, stream>>>(feat2, wth0, wtl0, b3_0, y0, 1024, 40, 40);
    conv3x3_mfma<<<dim3(50, 4, 2),  256, 0, stream>>>(feat1, wth1, wtl1, b3_1, y1, 512, 80, 80);
    conv3x3_mfma<<<dim3(200, 2, 1), 256, 0, stream>>>(feat0, wth2, wtl2, b3_2, y2, 256, 160, 160);

    // objectness-only 1x1 + keys
    obj_kernel<<<7,   256, 0, stream>>>(y0, w1_0, b1_0, keys, 1024, 1600, 0);
    obj_kernel<<<25,  256, 0, stream>>>(y1, w1_1, b1_1, keys, 512, 6400, 4800);
    obj_kernel<<<100, 256, 0, stream>>>(y2, w1_2, b1_2, keys, 256, 25600, 24000);

    // top-256
    hist_kernel<<<(NBOX + 255) / 256, 256, 0, stream>>>(keys, hist, NBOX);
    select_kernel<<<1, 256, 0, stream>>>(hist, meta);
    compact_kernel<<<(NBOX + 255) / 256, 256, 0, stream>>>(keys, NBOX, meta, cand, meta + 2);
    sort_select_kernel<<<1, 1024, 0, stream>>>(cand, meta, sel);

    // full 85-channel compute + decode for winners only
    final_kernel<<<256, 256, 0, stream>>>(y0, y1, y2, w1_0, w1_1, w1_2,
                                          b1_0, b1_1, b1_2, sel, (float*)d_out);
}